// Round 8
// baseline (422.260 us; speedup 1.0000x reference)
//
#include <hip/hip_runtime.h>

typedef unsigned short u16;
typedef unsigned int u32;
typedef __attribute__((ext_vector_type(4))) float f32x4;
typedef __attribute__((ext_vector_type(8))) short s16x8;
typedef __attribute__((ext_vector_type(4))) u16 u16x4;
typedef __attribute__((ext_vector_type(4))) u32 u32x4;

#define SCALE_LOG2E (0.125f * 1.44269504088896340736f)
#define NEGBIG (-3.0e38f)

__device__ inline u16 f2bf(float f) {
  u32 u = __builtin_bit_cast(u32, f);
  u += 0x7fffu + ((u >> 16) & 1u);
  return (u16)(u >> 16);
}

// ---------------- kernel 0: W f32 -> bf16, transposed [n][k], Wq pre-scaled ----
// Wt layout: [192][768] bf16, n = 0..63 Q (scaled by SCALE*LOG2E), 64..127 K, 128..191 V
__global__ void wconv_kernel(const float* __restrict__ Wq, const float* __restrict__ Wk,
                             const float* __restrict__ Wv, u16* __restrict__ Wt) {
  int base = blockIdx.x * 1024 + threadIdx.x;
  #pragma unroll
  for (int i = 0; i < 4; ++i) {
    int idx = base + i * 256;           // 144*1024 = 147456 = 192*768
    int n = idx / 768, k = idx - n * 768;
    int m = n >> 6, c = n & 63;
    const float* W = (m == 0) ? Wq : (m == 1 ? Wk : Wv);
    float v = W[k * 64 + c];
    if (m == 0) v *= SCALE_LOG2E;
    Wt[idx] = f2bf(v);
  }
}

// ---------------- kernel 1: QKV projection -----------------------------------
// grid 256 blocks (BM=64), 512 threads = 8 waves: wave = (mg 0..3, nh 0..1)
// Q: [b][s][64] bf16 (scaled), K: [b][s][64] bf16, Vt: [b][64][4096] bf16
__global__ __launch_bounds__(512) void proj_kernel(const float* __restrict__ x,
                                                   const u16* __restrict__ Wt,
                                                   u16* __restrict__ Qs,
                                                   u16* __restrict__ Kb,
                                                   u16* __restrict__ Vt) {
  __shared__ __align__(16) u16 xT[64 * 64];    // [row][64 k] bf16, chunk-swizzled
  __shared__ __align__(16) u16 Wl[192 * 64];   // [n][64 k] bf16, chunk-swizzled

  const int t = threadIdx.x;
  const int lane = t & 63;
  const int wv = t >> 6;
  const int c15 = lane & 15, g = lane >> 4;
  const int mg = wv >> 1, nh = wv & 1;
  const int m0 = blockIdx.x * 64;

  f32x4 acc[6];
  #pragma unroll
  for (int f = 0; f < 6; ++f) acc[f] = 0.0f;

  const int xr = t >> 3;           // 0..63
  const int xc = (t & 7) * 8;      // 0..56

  for (int kt = 0; kt < 12; ++kt) {
    const int k0 = kt * 64;
    // ---- issue global loads (before barrier) ----
    const float* xp = x + (size_t)(m0 + xr) * 768 + k0 + xc;
    f32x4 a0 = *(const f32x4*)(xp);
    f32x4 a1 = *(const f32x4*)(xp + 4);
    u32x4 wch[3];
    #pragma unroll
    for (int i = 0; i < 3; ++i) {
      int ci = t + i * 512;                 // 0..1535
      int rw = ci >> 3, ch = ci & 7;
      wch[i] = *(const u32x4*)(Wt + rw * 768 + k0 + ch * 8);
    }
    __syncthreads();   // prev iter's reads done
    // ---- x -> bf16 LDS (one b128 per thread), chunk ^= row&7 swizzle ----
    {
      u32x4 px;
      px.x = (u32)f2bf(a0.x) | ((u32)f2bf(a0.y) << 16);
      px.y = (u32)f2bf(a0.z) | ((u32)f2bf(a0.w) << 16);
      px.z = (u32)f2bf(a1.x) | ((u32)f2bf(a1.y) << 16);
      px.w = (u32)f2bf(a1.z) | ((u32)f2bf(a1.w) << 16);
      int ch = t & 7;
      int sw = ch ^ (xr & 7);
      *(u32x4*)(&xT[xr * 64 + sw * 8]) = px;
    }
    // ---- W chunks -> LDS ----
    #pragma unroll
    for (int i = 0; i < 3; ++i) {
      int ci = t + i * 512;
      int rw = ci >> 3, ch = ci & 7;
      int sw = ch ^ (rw & 7);
      *(u32x4*)(&Wl[rw * 64 + sw * 8]) = wch[i];
    }
    __syncthreads();
    // ---- MFMA ----
    #pragma unroll
    for (int kk = 0; kk < 2; ++kk) {
      const int arow = 16 * mg + c15;
      s16x8 af = *(const s16x8*)(&xT[arow * 64 + (((kk * 4 + g) ^ (arow & 7)) * 8)]);
      #pragma unroll
      for (int f = 0; f < 6; ++f) {
        const int brow = 96 * nh + 16 * f + c15;
        s16x8 bf = *(const s16x8*)(&Wl[brow * 64 + (((kk * 4 + g) ^ (brow & 7)) * 8)]);
        acc[f] = __builtin_amdgcn_mfma_f32_16x16x32_bf16(af, bf, acc[f], 0, 0, 0);
      }
    }
  }

  // ---- store: D row = 4g+j (+16mg), col = c15 (+16f +96nh) ----
  const int b = m0 >> 12;
  const int s0 = m0 & 4095;
  const int mbase = m0 + 16 * mg + 4 * g;
  #pragma unroll
  for (int f = 0; f < 6; ++f) {
    const int n16 = 96 * nh + 16 * f;
    if (n16 < 64) {
      const int coln = n16 + c15;
      #pragma unroll
      for (int j = 0; j < 4; ++j)
        Qs[(size_t)(mbase + j) * 64 + coln] = f2bf(acc[f][j]);
    } else if (n16 < 128) {
      const int coln = n16 - 64 + c15;
      #pragma unroll
      for (int j = 0; j < 4; ++j)
        Kb[(size_t)(mbase + j) * 64 + coln] = f2bf(acc[f][j]);
    } else {
      const int d = n16 - 128 + c15;
      u16x4 pk;
      pk.x = f2bf(acc[f][0]); pk.y = f2bf(acc[f][1]);
      pk.z = f2bf(acc[f][2]); pk.w = f2bf(acc[f][3]);
      *(u16x4*)(Vt + (size_t)(b * 64 + d) * 4096 + s0 + 16 * mg + 4 * g) = pk;
    }
  }
}

// ---------------- kernel 2: causal flash attention ---------------------------
// 512 blocks of 1 wave. block -> (batch b, q-tile of 32 rows). Largest qb first.
__global__ __launch_bounds__(64) void attn_kernel(const u16* __restrict__ Qs,
                                                  const u16* __restrict__ Kb,
                                                  const u16* __restrict__ Vt,
                                                  float* __restrict__ out) {
  __shared__ __align__(16) u16 P[32 * 72];   // [q row][kv] bf16, padded stride 72

  const int lane = threadIdx.x;
  const int c15 = lane & 15, g = lane >> 4;
  const int bid = blockIdx.x;
  const int qb = 127 - (bid >> 2);   // big blocks dispatched first
  const int b = bid & 3;
  const int q0 = qb * 32;

  const u16* Qb  = Qs + (size_t)b * 4096 * 64;
  const u16* Kbb = Kb + (size_t)b * 4096 * 64;
  const u16* Vtb = Vt + (size_t)b * 64 * 4096;

  // Q fragments in registers: A[q = c15 (+16r)][d = 32kk+8g+e]
  s16x8 qf[2][2];
  #pragma unroll
  for (int r = 0; r < 2; ++r)
    #pragma unroll
    for (int kk = 0; kk < 2; ++kk)
      qf[r][kk] = *(const s16x8*)(Qb + (size_t)(q0 + 16 * r + c15) * 64 + 32 * kk + 8 * g);

  f32x4 o[2][4];
  float mrow[2][4], lrow[2][4];
  #pragma unroll
  for (int r = 0; r < 2; ++r)
    #pragma unroll
    for (int j = 0; j < 4; ++j) {
      o[r][j] = 0.0f; mrow[r][j] = NEGBIG; lrow[r][j] = 0.0f;
    }

  const int T = (qb >> 1) + 1;       // kv tiles of 64
  for (int tile = 0; tile < T; ++tile) {
    const int kv0 = tile * 64;
    // ---- S = Q K^T (pre-scaled by SCALE*log2e) ----
    f32x4 s[2][4];
    #pragma unroll
    for (int r = 0; r < 2; ++r)
      #pragma unroll
      for (int f = 0; f < 4; ++f) s[r][f] = 0.0f;
    #pragma unroll
    for (int kk = 0; kk < 2; ++kk) {
      s16x8 kf[4];
      #pragma unroll
      for (int f = 0; f < 4; ++f)
        kf[f] = *(const s16x8*)(Kbb + (size_t)(kv0 + 16 * f + c15) * 64 + 32 * kk + 8 * g);
      #pragma unroll
      for (int r = 0; r < 2; ++r)
        #pragma unroll
        for (int f = 0; f < 4; ++f)
          s[r][f] = __builtin_amdgcn_mfma_f32_16x16x32_bf16(qf[r][kk], kf[f], s[r][f], 0, 0, 0);
    }
    // ---- causal mask (diagonal tiles only) ----
    if (kv0 + 63 > q0) {
      #pragma unroll
      for (int r = 0; r < 2; ++r)
        #pragma unroll
        for (int f = 0; f < 4; ++f) {
          const int kcol = kv0 + 16 * f + c15;
          #pragma unroll
          for (int j = 0; j < 4; ++j) {
            const int qrow = q0 + 16 * r + 4 * g + j;
            if (kcol > qrow) s[r][f][j] = NEGBIG;
          }
        }
    }
    // ---- online softmax (rows = 4g+j per 16-group; cols spread over 16 lanes) ----
    #pragma unroll
    for (int r = 0; r < 2; ++r)
      #pragma unroll
      for (int j = 0; j < 4; ++j) {
        float mx = fmaxf(fmaxf(s[r][0][j], s[r][1][j]), fmaxf(s[r][2][j], s[r][3][j]));
        mx = fmaxf(mx, __shfl_xor(mx, 1));
        mx = fmaxf(mx, __shfl_xor(mx, 2));
        mx = fmaxf(mx, __shfl_xor(mx, 4));
        mx = fmaxf(mx, __shfl_xor(mx, 8));
        const float mn = fmaxf(mrow[r][j], mx);
        const float al = exp2f(mrow[r][j] - mn);
        float ps[4], sum = 0.0f;
        #pragma unroll
        for (int f = 0; f < 4; ++f) { ps[f] = exp2f(s[r][f][j] - mn); sum += ps[f]; }
        sum += __shfl_xor(sum, 1);
        sum += __shfl_xor(sum, 2);
        sum += __shfl_xor(sum, 4);
        sum += __shfl_xor(sum, 8);
        lrow[r][j] = lrow[r][j] * al + sum;
        mrow[r][j] = mn;
        #pragma unroll
        for (int fd = 0; fd < 4; ++fd) o[r][fd][j] *= al;
        // P -> bf16 LDS: pack col pairs via shfl, even lanes write b32
        const int prow = 16 * r + 4 * g + j;
        #pragma unroll
        for (int f = 0; f < 4; ++f) {
          const float pn = __shfl_xor(ps[f], 1);
          if (!(lane & 1)) {
            const u32 pk = (u32)f2bf(ps[f]) | ((u32)f2bf(pn) << 16);
            *(u32*)(&P[prow * 72 + 16 * f + c15]) = pk;
          }
        }
      }
    // ---- O += P V ----
    #pragma unroll
    for (int kk = 0; kk < 2; ++kk) {
      s16x8 pa[2];
      #pragma unroll
      for (int r = 0; r < 2; ++r)
        pa[r] = *(const s16x8*)(&P[(16 * r + c15) * 72 + 32 * kk + 8 * g]);
      s16x8 vf[4];
      #pragma unroll
      for (int f = 0; f < 4; ++f)
        vf[f] = *(const s16x8*)(Vtb + (size_t)(16 * f + c15) * 4096 + kv0 + 32 * kk + 8 * g);
      #pragma unroll
      for (int r = 0; r < 2; ++r)
        #pragma unroll
        for (int f = 0; f < 4; ++f)
          o[r][f] = __builtin_amdgcn_mfma_f32_16x16x32_bf16(pa[r], vf[f], o[r][f], 0, 0, 0);
    }
  }
  // ---- epilogue: out[q][d] = o / l ----
  #pragma unroll
  for (int r = 0; r < 2; ++r)
    #pragma unroll
    for (int f = 0; f < 4; ++f)
      #pragma unroll
      for (int j = 0; j < 4; ++j) {
        const int q = q0 + 16 * r + 4 * g + j;
        out[(size_t)(b * 4096 + q) * 64 + 16 * f + c15] = o[r][f][j] / lrow[r][j];
      }
}

// ---------------- launch ------------------------------------------------------
extern "C" void kernel_launch(void* const* d_in, const int* in_sizes, int n_in,
                              void* d_out, int out_size, void* d_ws, size_t ws_size,
                              hipStream_t stream) {
  const float* x  = (const float*)d_in[0];
  const float* Wq = (const float*)d_in[1];
  const float* Wk = (const float*)d_in[2];
  const float* Wv = (const float*)d_in[3];
  float* out = (float*)d_out;

  char* ws = (char*)d_ws;
  u16* Wt = (u16*)(ws);                 // 294912 B
  u16* Qs = (u16*)(ws + 524288);        // 2 MB
  u16* Kb = (u16*)(ws + 2621440);       // 2 MB
  u16* Vt = (u16*)(ws + 4718592);       // 2 MB (transposed [b][64][4096])

  wconv_kernel<<<144, 256, 0, stream>>>(Wq, Wk, Wv, Wt);
  proj_kernel<<<256, 512, 0, stream>>>(x, Wt, Qs, Kb, Vt);
  attn_kernel<<<512, 64, 0, stream>>>(Qs, Kb, Vt, out);
}

// Round 12
// 193.403 us; speedup vs baseline: 2.1833x; 2.1833x over previous
//
#include <hip/hip_runtime.h>

typedef unsigned short u16;
typedef unsigned int u32;
typedef __attribute__((ext_vector_type(4))) float f32x4;
typedef __attribute__((ext_vector_type(8))) short s16x8;
typedef __attribute__((ext_vector_type(4))) u16 u16x4;
typedef __attribute__((ext_vector_type(4))) u32 u32x4;

#define SCALE_LOG2E (0.125f * 1.44269504088896340736f)
#define NEGBIG (-3.0e38f)

__device__ inline u16 f2bf(float f) {
  u32 u = __builtin_bit_cast(u32, f);
  u += 0x7fffu + ((u >> 16) & 1u);
  return (u16)(u >> 16);
}

// ---------------- kernel 0: W f32 -> bf16, transposed [n][k], Wq pre-scaled ----
__global__ void wconv_kernel(const float* __restrict__ Wq, const float* __restrict__ Wk,
                             const float* __restrict__ Wv, u16* __restrict__ Wt) {
  int base = blockIdx.x * 1024 + threadIdx.x;
  #pragma unroll
  for (int i = 0; i < 4; ++i) {
    int idx = base + i * 256;           // 144*1024 = 147456 = 192*768
    int n = idx / 768, k = idx - n * 768;
    int m = n >> 6, c = n & 63;
    const float* W = (m == 0) ? Wq : (m == 1 ? Wk : Wv);
    float v = W[k * 64 + c];
    if (m == 0) v *= SCALE_LOG2E;
    Wt[idx] = f2bf(v);
  }
}

// ---------------- kernel 1: QKV projection (unchanged) ------------------------
__global__ __launch_bounds__(512) void proj_kernel(const float* __restrict__ x,
                                                   const u16* __restrict__ Wt,
                                                   u16* __restrict__ Qs,
                                                   u16* __restrict__ Kb,
                                                   u16* __restrict__ Vt) {
  __shared__ __align__(16) u16 xT[64 * 64];
  __shared__ __align__(16) u16 Wl[192 * 64];

  const int t = threadIdx.x;
  const int lane = t & 63;
  const int wv = t >> 6;
  const int c15 = lane & 15, g = lane >> 4;
  const int mg = wv >> 1, nh = wv & 1;
  const int m0 = blockIdx.x * 64;

  f32x4 acc[6];
  #pragma unroll
  for (int f = 0; f < 6; ++f) acc[f] = 0.0f;

  const int xr = t >> 3;
  const int xc = (t & 7) * 8;

  for (int kt = 0; kt < 12; ++kt) {
    const int k0 = kt * 64;
    const float* xp = x + (size_t)(m0 + xr) * 768 + k0 + xc;
    f32x4 a0 = *(const f32x4*)(xp);
    f32x4 a1 = *(const f32x4*)(xp + 4);
    u32x4 wch[3];
    #pragma unroll
    for (int i = 0; i < 3; ++i) {
      int ci = t + i * 512;
      int rw = ci >> 3, ch = ci & 7;
      wch[i] = *(const u32x4*)(Wt + rw * 768 + k0 + ch * 8);
    }
    __syncthreads();
    {
      u32x4 px;
      px.x = (u32)f2bf(a0.x) | ((u32)f2bf(a0.y) << 16);
      px.y = (u32)f2bf(a0.z) | ((u32)f2bf(a0.w) << 16);
      px.z = (u32)f2bf(a1.x) | ((u32)f2bf(a1.y) << 16);
      px.w = (u32)f2bf(a1.z) | ((u32)f2bf(a1.w) << 16);
      int ch = t & 7;
      int sw = ch ^ (xr & 7);
      *(u32x4*)(&xT[xr * 64 + sw * 8]) = px;
    }
    #pragma unroll
    for (int i = 0; i < 3; ++i) {
      int ci = t + i * 512;
      int rw = ci >> 3, ch = ci & 7;
      int sw = ch ^ (rw & 7);
      *(u32x4*)(&Wl[rw * 64 + sw * 8]) = wch[i];
    }
    __syncthreads();
    #pragma unroll
    for (int kk = 0; kk < 2; ++kk) {
      const int arow = 16 * mg + c15;
      s16x8 af = *(const s16x8*)(&xT[arow * 64 + (((kk * 4 + g) ^ (arow & 7)) * 8)]);
      #pragma unroll
      for (int f = 0; f < 6; ++f) {
        const int brow = 96 * nh + 16 * f + c15;
        s16x8 bf = *(const s16x8*)(&Wl[brow * 64 + (((kk * 4 + g) ^ (brow & 7)) * 8)]);
        acc[f] = __builtin_amdgcn_mfma_f32_16x16x32_bf16(af, bf, acc[f], 0, 0, 0);
      }
    }
  }

  const int b = m0 >> 12;
  const int s0 = m0 & 4095;
  const int mbase = m0 + 16 * mg + 4 * g;
  #pragma unroll
  for (int f = 0; f < 6; ++f) {
    const int n16 = 96 * nh + 16 * f;
    if (n16 < 64) {
      const int coln = n16 + c15;
      #pragma unroll
      for (int j = 0; j < 4; ++j)
        Qs[(size_t)(mbase + j) * 64 + coln] = f2bf(acc[f][j]);
    } else if (n16 < 128) {
      const int coln = n16 - 64 + c15;
      #pragma unroll
      for (int j = 0; j < 4; ++j)
        Kb[(size_t)(mbase + j) * 64 + coln] = f2bf(acc[f][j]);
    } else {
      const int d = n16 - 128 + c15;
      u16x4 pk;
      pk.x = f2bf(acc[f][0]); pk.y = f2bf(acc[f][1]);
      pk.z = f2bf(acc[f][2]); pk.w = f2bf(acc[f][3]);
      *(u16x4*)(Vt + (size_t)(b * 64 + d) * 4096 + s0 + 16 * mg + 4 * g) = pk;
    }
  }
}

// ---------------- kernel 2: causal flash attention, intra-block KV split ------
// 512 blocks of 4 waves (256 thr). Block -> (batch b, q-tile of 32 rows).
// Wave w processes KV tiles w, w+4, w+8, ... with private online-softmax state;
// partials merged in LDS at the end (exact in f32).
__global__ __launch_bounds__(256) void attn_kernel(const u16* __restrict__ Qs,
                                                   const u16* __restrict__ Kb,
                                                   const u16* __restrict__ Vt,
                                                   float* __restrict__ out) {
  // union: during KV loop, per-wave P buffers [w][32*72] u16 (18.4 KB);
  // after __syncthreads, o-slabs [4][32][64] f32 (32 KB) + stats.
  __shared__ __align__(16) char smem[4 * 32 * 64 * 4 + 2 * 4 * 32 * 4];
  float* osl = (float*)smem;                       // [4][32][64]
  float* msh = (float*)(smem + 32768);             // [4][32]
  float* lsh = (float*)(smem + 32768 + 512);       // [4][32]

  const int t = threadIdx.x;
  const int lane = t & 63;
  const int w = t >> 6;                            // wave 0..3
  const int c15 = lane & 15, g = lane >> 4;
  const int bid = blockIdx.x;
  const int qb = 127 - (bid >> 2);                 // big blocks dispatched first
  const int b = bid & 3;
  const int q0 = qb * 32;

  u16* P = (u16*)smem + w * (32 * 72);             // per-wave P, padded stride 72

  const u16* Qb  = Qs + (size_t)b * 4096 * 64;
  const u16* Kbb = Kb + (size_t)b * 4096 * 64;
  const u16* Vtb = Vt + (size_t)b * 64 * 4096;

  // Q fragments in registers: A[q = c15 (+16r)][d = 32kk+8g+e]
  s16x8 qf[2][2];
  #pragma unroll
  for (int r = 0; r < 2; ++r)
    #pragma unroll
    for (int kk = 0; kk < 2; ++kk)
      qf[r][kk] = *(const s16x8*)(Qb + (size_t)(q0 + 16 * r + c15) * 64 + 32 * kk + 8 * g);

  f32x4 o[2][4];
  float mrow[2][4], lrow[2][4];
  #pragma unroll
  for (int r = 0; r < 2; ++r)
    #pragma unroll
    for (int j = 0; j < 4; ++j) {
      o[r][j] = 0.0f; mrow[r][j] = NEGBIG; lrow[r][j] = 0.0f;
    }

  const int T = (qb >> 1) + 1;                     // kv tiles of 64
  for (int tile = w; tile < T; tile += 4) {
    const int kv0 = tile * 64;
    // ---- S = Q K^T (pre-scaled by SCALE*log2e) ----
    f32x4 s[2][4];
    #pragma unroll
    for (int r = 0; r < 2; ++r)
      #pragma unroll
      for (int f = 0; f < 4; ++f) s[r][f] = 0.0f;
    #pragma unroll
    for (int kk = 0; kk < 2; ++kk) {
      s16x8 kf[4];
      #pragma unroll
      for (int f = 0; f < 4; ++f)
        kf[f] = *(const s16x8*)(Kbb + (size_t)(kv0 + 16 * f + c15) * 64 + 32 * kk + 8 * g);
      #pragma unroll
      for (int r = 0; r < 2; ++r)
        #pragma unroll
        for (int f = 0; f < 4; ++f)
          s[r][f] = __builtin_amdgcn_mfma_f32_16x16x32_bf16(qf[r][kk], kf[f], s[r][f], 0, 0, 0);
    }
    // ---- causal mask (diagonal tiles only) ----
    if (kv0 + 63 > q0) {
      #pragma unroll
      for (int r = 0; r < 2; ++r)
        #pragma unroll
        for (int f = 0; f < 4; ++f) {
          const int kcol = kv0 + 16 * f + c15;
          #pragma unroll
          for (int j = 0; j < 4; ++j) {
            const int qrow = q0 + 16 * r + 4 * g + j;
            if (kcol > qrow) s[r][f][j] = NEGBIG;
          }
        }
    }
    // ---- online softmax ----
    #pragma unroll
    for (int r = 0; r < 2; ++r)
      #pragma unroll
      for (int j = 0; j < 4; ++j) {
        float mx = fmaxf(fmaxf(s[r][0][j], s[r][1][j]), fmaxf(s[r][2][j], s[r][3][j]));
        mx = fmaxf(mx, __shfl_xor(mx, 1));
        mx = fmaxf(mx, __shfl_xor(mx, 2));
        mx = fmaxf(mx, __shfl_xor(mx, 4));
        mx = fmaxf(mx, __shfl_xor(mx, 8));
        const float mn = fmaxf(mrow[r][j], mx);
        const float al = exp2f(mrow[r][j] - mn);
        float ps[4], sum = 0.0f;
        #pragma unroll
        for (int f = 0; f < 4; ++f) { ps[f] = exp2f(s[r][f][j] - mn); sum += ps[f]; }
        sum += __shfl_xor(sum, 1);
        sum += __shfl_xor(sum, 2);
        sum += __shfl_xor(sum, 4);
        sum += __shfl_xor(sum, 8);
        lrow[r][j] = lrow[r][j] * al + sum;
        mrow[r][j] = mn;
        #pragma unroll
        for (int fd = 0; fd < 4; ++fd) o[r][fd][j] *= al;
        const int prow = 16 * r + 4 * g + j;
        #pragma unroll
        for (int f = 0; f < 4; ++f) {
          const float pn = __shfl_xor(ps[f], 1);
          if (!(lane & 1)) {
            const u32 pk = (u32)f2bf(ps[f]) | ((u32)f2bf(pn) << 16);
            *(u32*)(&P[prow * 72 + 16 * f + c15]) = pk;
          }
        }
      }
    // ---- O += P V ----
    #pragma unroll
    for (int kk = 0; kk < 2; ++kk) {
      s16x8 pa[2];
      #pragma unroll
      for (int r = 0; r < 2; ++r)
        pa[r] = *(const s16x8*)(&P[(16 * r + c15) * 72 + 32 * kk + 8 * g]);
      s16x8 vf[4];
      #pragma unroll
      for (int f = 0; f < 4; ++f)
        vf[f] = *(const s16x8*)(Vtb + (size_t)(16 * f + c15) * 4096 + kv0 + 32 * kk + 8 * g);
      #pragma unroll
      for (int r = 0; r < 2; ++r)
        #pragma unroll
        for (int f = 0; f < 4; ++f)
          o[r][f] = __builtin_amdgcn_mfma_f32_16x16x32_bf16(pa[r], vf[f], o[r][f], 0, 0, 0);
    }
  }

  // ---- all waves done with P before slabs overwrite the union ----
  __syncthreads();

  // per-wave stats + o slab to LDS
  if (c15 == 0) {
    #pragma unroll
    for (int r = 0; r < 2; ++r)
      #pragma unroll
      for (int j = 0; j < 4; ++j) {
        const int row = 16 * r + 4 * g + j;
        msh[w * 32 + row] = mrow[r][j];
        lsh[w * 32 + row] = lrow[r][j];
      }
  }
  #pragma unroll
  for (int r = 0; r < 2; ++r)
    #pragma unroll
    for (int f = 0; f < 4; ++f)
      #pragma unroll
      for (int j = 0; j < 4; ++j) {
        const int row = 16 * r + 4 * g + j;
        osl[(w * 32 + row) * 64 + 16 * f + c15] = o[r][f][j];
      }
  __syncthreads();

  // merge: 256 threads; thread -> (row = t>>3, cols 8*(t&7)..+7)
  {
    const int row = t >> 3;
    const int cb = (t & 7) * 8;
    float m0v = msh[row], m1v = msh[32 + row], m2v = msh[64 + row], m3v = msh[96 + row];
    float M = fmaxf(fmaxf(m0v, m1v), fmaxf(m2v, m3v));
    float a0 = exp2f(m0v - M), a1 = exp2f(m1v - M), a2 = exp2f(m2v - M), a3 = exp2f(m3v - M);
    float L = a0 * lsh[row] + a1 * lsh[32 + row] + a2 * lsh[64 + row] + a3 * lsh[96 + row];
    const float inv = 1.0f / L;
    float* op = out + (size_t)(b * 4096 + q0 + row) * 64 + cb;
    #pragma unroll
    for (int c = 0; c < 8; ++c) {
      float v = a0 * osl[(row) * 64 + cb + c] + a1 * osl[(32 + row) * 64 + cb + c] +
                a2 * osl[(64 + row) * 64 + cb + c] + a3 * osl[(96 + row) * 64 + cb + c];
      op[c] = v * inv;
    }
  }
}

// ---------------- launch ------------------------------------------------------
extern "C" void kernel_launch(void* const* d_in, const int* in_sizes, int n_in,
                              void* d_out, int out_size, void* d_ws, size_t ws_size,
                              hipStream_t stream) {
  const float* x  = (const float*)d_in[0];
  const float* Wq = (const float*)d_in[1];
  const float* Wk = (const float*)d_in[2];
  const float* Wv = (const float*)d_in[3];
  float* out = (float*)d_out;

  char* ws = (char*)d_ws;
  u16* Wt = (u16*)(ws);                 // 294912 B
  u16* Qs = (u16*)(ws + 524288);        // 2 MB
  u16* Kb = (u16*)(ws + 2621440);       // 2 MB
  u16* Vt = (u16*)(ws + 4718592);       // 2 MB (transposed [b][64][4096])

  wconv_kernel<<<144, 256, 0, stream>>>(Wq, Wk, Wv, Wt);
  proj_kernel<<<256, 512, 0, stream>>>(x, Wt, Qs, Kb, Vt);
  attn_kernel<<<512, 256, 0, stream>>>(Qs, Kb, Vt, out);
}

// Round 13
// 184.707 us; speedup vs baseline: 2.2861x; 1.0471x over previous
//
#include <hip/hip_runtime.h>

typedef unsigned short u16;
typedef unsigned int u32;
typedef __attribute__((ext_vector_type(4))) float f32x4;
typedef __attribute__((ext_vector_type(8))) short s16x8;
typedef __attribute__((ext_vector_type(4))) u16 u16x4;
typedef __attribute__((ext_vector_type(4))) u32 u32x4;

#define SCALE_LOG2E (0.125f * 1.44269504088896340736f)
#define NEGBIG (-3.0e38f)

__device__ inline u16 f2bf(float f) {
  u32 u = __builtin_bit_cast(u32, f);
  u += 0x7fffu + ((u >> 16) & 1u);
  return (u16)(u >> 16);
}

// ---------------- kernel 0: W f32 -> bf16, transposed [n][k], Wq pre-scaled ----
__global__ void wconv_kernel(const float* __restrict__ Wq, const float* __restrict__ Wk,
                             const float* __restrict__ Wv, u16* __restrict__ Wt) {
  int base = blockIdx.x * 1024 + threadIdx.x;
  #pragma unroll
  for (int i = 0; i < 4; ++i) {
    int idx = base + i * 256;           // 144*1024 = 147456 = 192*768
    int n = idx / 768, k = idx - n * 768;
    int m = n >> 6, c = n & 63;
    const float* W = (m == 0) ? Wq : (m == 1 ? Wk : Wv);
    float v = W[k * 64 + c];
    if (m == 0) v *= SCALE_LOG2E;
    Wt[idx] = f2bf(v);
  }
}

// ---------------- kernel 1: QKV projection, software-prefetched ---------------
// grid 256 blocks (BM=64), 512 threads. Loads for tile kt+1 issue right after
// tile kt's LDS writes -> HBM latency overlaps MFMA phase instead of being
// serially exposed every iteration.
__global__ __launch_bounds__(512) void proj_kernel(const float* __restrict__ x,
                                                   const u16* __restrict__ Wt,
                                                   u16* __restrict__ Qs,
                                                   u16* __restrict__ Kb,
                                                   u16* __restrict__ Vt) {
  __shared__ __align__(16) u16 xT[64 * 64];
  __shared__ __align__(16) u16 Wl[192 * 64];

  const int t = threadIdx.x;
  const int lane = t & 63;
  const int wv = t >> 6;
  const int c15 = lane & 15, g = lane >> 4;
  const int mg = wv >> 1, nh = wv & 1;
  const int m0 = blockIdx.x * 64;

  f32x4 acc[6];
  #pragma unroll
  for (int f = 0; f < 6; ++f) acc[f] = 0.0f;

  const int xr = t >> 3;
  const int xc = (t & 7) * 8;

  // preload kt = 0
  f32x4 a0, a1;
  u32x4 wch[3];
  {
    const float* xp = x + (size_t)(m0 + xr) * 768 + xc;
    a0 = *(const f32x4*)(xp);
    a1 = *(const f32x4*)(xp + 4);
    #pragma unroll
    for (int i = 0; i < 3; ++i) {
      int ci = t + i * 512;
      int rw = ci >> 3, ch = ci & 7;
      wch[i] = *(const u32x4*)(Wt + rw * 768 + ch * 8);
    }
  }

  for (int kt = 0; kt < 12; ++kt) {
    __syncthreads();   // prev iter's LDS reads done
    // ---- write current tile to LDS ----
    {
      u32x4 px;
      px.x = (u32)f2bf(a0.x) | ((u32)f2bf(a0.y) << 16);
      px.y = (u32)f2bf(a0.z) | ((u32)f2bf(a0.w) << 16);
      px.z = (u32)f2bf(a1.x) | ((u32)f2bf(a1.y) << 16);
      px.w = (u32)f2bf(a1.z) | ((u32)f2bf(a1.w) << 16);
      int ch = t & 7;
      int sw = ch ^ (xr & 7);
      *(u32x4*)(&xT[xr * 64 + sw * 8]) = px;
    }
    #pragma unroll
    for (int i = 0; i < 3; ++i) {
      int ci = t + i * 512;
      int rw = ci >> 3, ch = ci & 7;
      int sw = ch ^ (rw & 7);
      *(u32x4*)(&Wl[rw * 64 + sw * 8]) = wch[i];
    }
    // ---- prefetch next tile (overlaps barrier + MFMA) ----
    if (kt < 11) {
      const int k0 = (kt + 1) * 64;
      const float* xp = x + (size_t)(m0 + xr) * 768 + k0 + xc;
      a0 = *(const f32x4*)(xp);
      a1 = *(const f32x4*)(xp + 4);
      #pragma unroll
      for (int i = 0; i < 3; ++i) {
        int ci = t + i * 512;
        int rw = ci >> 3, ch = ci & 7;
        wch[i] = *(const u32x4*)(Wt + rw * 768 + k0 + ch * 8);
      }
    }
    __syncthreads();
    // ---- MFMA ----
    #pragma unroll
    for (int kk = 0; kk < 2; ++kk) {
      const int arow = 16 * mg + c15;
      s16x8 af = *(const s16x8*)(&xT[arow * 64 + (((kk * 4 + g) ^ (arow & 7)) * 8)]);
      #pragma unroll
      for (int f = 0; f < 6; ++f) {
        const int brow = 96 * nh + 16 * f + c15;
        s16x8 bf = *(const s16x8*)(&Wl[brow * 64 + (((kk * 4 + g) ^ (brow & 7)) * 8)]);
        acc[f] = __builtin_amdgcn_mfma_f32_16x16x32_bf16(af, bf, acc[f], 0, 0, 0);
      }
    }
  }

  const int b = m0 >> 12;
  const int s0 = m0 & 4095;
  const int mbase = m0 + 16 * mg + 4 * g;
  #pragma unroll
  for (int f = 0; f < 6; ++f) {
    const int n16 = 96 * nh + 16 * f;
    if (n16 < 64) {
      const int coln = n16 + c15;
      #pragma unroll
      for (int j = 0; j < 4; ++j)
        Qs[(size_t)(mbase + j) * 64 + coln] = f2bf(acc[f][j]);
    } else if (n16 < 128) {
      const int coln = n16 - 64 + c15;
      #pragma unroll
      for (int j = 0; j < 4; ++j)
        Kb[(size_t)(mbase + j) * 64 + coln] = f2bf(acc[f][j]);
    } else {
      const int d = n16 - 128 + c15;
      u16x4 pk;
      pk.x = f2bf(acc[f][0]); pk.y = f2bf(acc[f][1]);
      pk.z = f2bf(acc[f][2]); pk.w = f2bf(acc[f][3]);
      *(u16x4*)(Vt + (size_t)(b * 64 + d) * 4096 + s0 + 16 * mg + 4 * g) = pk;
    }
  }
}

// ---------------- kernel 2: causal flash attention, 8-wave KV split -----------
// 512 blocks of 8 waves (512 thr), all-resident (2 blocks/CU, 16 waves/CU).
// Wave w processes KV tiles w, w+8, ...; longest chain = ceil(64/8) = 8 tiles.
// Two-stage in-LDS merge: waves 4-7 publish -> waves 0-3 merge in-register ->
// final 4-way merge (exact in f32).
__global__ __launch_bounds__(512, 4) void attn_kernel(const u16* __restrict__ Qs,
                                                      const u16* __restrict__ Kb,
                                                      const u16* __restrict__ Vt,
                                                      float* __restrict__ out) {
  // union: during KV loop, per-wave P buffers [8][32*72] u16 (36864 B);
  // after the post-loop barrier, 4 slabs [4][32][64] f32 (32768) + stats (1024).
  __shared__ __align__(16) char smem[8 * 32 * 72 * 2];
  float* osl = (float*)smem;                       // [4][32][64]
  float* msh = (float*)(smem + 32768);             // [4][32]
  float* lsh = (float*)(smem + 32768 + 512);       // [4][32]

  const int t = threadIdx.x;
  const int lane = t & 63;
  const int w = t >> 6;                            // wave 0..7
  const int c15 = lane & 15, g = lane >> 4;
  const int bid = blockIdx.x;
  const int qb = 127 - (bid >> 2);                 // big blocks dispatched first
  const int b = bid & 3;
  const int q0 = qb * 32;

  u16* P = (u16*)smem + w * (32 * 72);             // per-wave P, padded stride 72

  const u16* Qb  = Qs + (size_t)b * 4096 * 64;
  const u16* Kbb = Kb + (size_t)b * 4096 * 64;
  const u16* Vtb = Vt + (size_t)b * 64 * 4096;

  // Q fragments in registers: A[q = c15 (+16r)][d = 32kk+8g+e]
  s16x8 qf[2][2];
  #pragma unroll
  for (int r = 0; r < 2; ++r)
    #pragma unroll
    for (int kk = 0; kk < 2; ++kk)
      qf[r][kk] = *(const s16x8*)(Qb + (size_t)(q0 + 16 * r + c15) * 64 + 32 * kk + 8 * g);

  f32x4 o[2][4];
  float mrow[2][4], lrow[2][4];
  #pragma unroll
  for (int r = 0; r < 2; ++r)
    #pragma unroll
    for (int j = 0; j < 4; ++j) {
      o[r][j] = 0.0f; mrow[r][j] = NEGBIG; lrow[r][j] = 0.0f;
    }

  const int T = (qb >> 1) + 1;                     // kv tiles of 64
  for (int tile = w; tile < T; tile += 8) {
    const int kv0 = tile * 64;
    // ---- S = Q K^T (pre-scaled by SCALE*log2e) ----
    f32x4 s[2][4];
    #pragma unroll
    for (int r = 0; r < 2; ++r)
      #pragma unroll
      for (int f = 0; f < 4; ++f) s[r][f] = 0.0f;
    #pragma unroll
    for (int kk = 0; kk < 2; ++kk) {
      s16x8 kf[4];
      #pragma unroll
      for (int f = 0; f < 4; ++f)
        kf[f] = *(const s16x8*)(Kbb + (size_t)(kv0 + 16 * f + c15) * 64 + 32 * kk + 8 * g);
      #pragma unroll
      for (int r = 0; r < 2; ++r)
        #pragma unroll
        for (int f = 0; f < 4; ++f)
          s[r][f] = __builtin_amdgcn_mfma_f32_16x16x32_bf16(qf[r][kk], kf[f], s[r][f], 0, 0, 0);
    }
    // ---- causal mask (diagonal tiles only) ----
    if (kv0 + 63 > q0) {
      #pragma unroll
      for (int r = 0; r < 2; ++r)
        #pragma unroll
        for (int f = 0; f < 4; ++f) {
          const int kcol = kv0 + 16 * f + c15;
          #pragma unroll
          for (int j = 0; j < 4; ++j) {
            const int qrow = q0 + 16 * r + 4 * g + j;
            if (kcol > qrow) s[r][f][j] = NEGBIG;
          }
        }
    }
    // ---- online softmax ----
    #pragma unroll
    for (int r = 0; r < 2; ++r)
      #pragma unroll
      for (int j = 0; j < 4; ++j) {
        float mx = fmaxf(fmaxf(s[r][0][j], s[r][1][j]), fmaxf(s[r][2][j], s[r][3][j]));
        mx = fmaxf(mx, __shfl_xor(mx, 1));
        mx = fmaxf(mx, __shfl_xor(mx, 2));
        mx = fmaxf(mx, __shfl_xor(mx, 4));
        mx = fmaxf(mx, __shfl_xor(mx, 8));
        const float mn = fmaxf(mrow[r][j], mx);
        const float al = exp2f(mrow[r][j] - mn);
        float ps[4], sum = 0.0f;
        #pragma unroll
        for (int f = 0; f < 4; ++f) { ps[f] = exp2f(s[r][f][j] - mn); sum += ps[f]; }
        sum += __shfl_xor(sum, 1);
        sum += __shfl_xor(sum, 2);
        sum += __shfl_xor(sum, 4);
        sum += __shfl_xor(sum, 8);
        lrow[r][j] = lrow[r][j] * al + sum;
        mrow[r][j] = mn;
        #pragma unroll
        for (int fd = 0; fd < 4; ++fd) o[r][fd][j] *= al;
        const int prow = 16 * r + 4 * g + j;
        #pragma unroll
        for (int f = 0; f < 4; ++f) {
          const float pn = __shfl_xor(ps[f], 1);
          if (!(lane & 1)) {
            const u32 pk = (u32)f2bf(ps[f]) | ((u32)f2bf(pn) << 16);
            *(u32*)(&P[prow * 72 + 16 * f + c15]) = pk;
          }
        }
      }
    // ---- O += P V ----
    #pragma unroll
    for (int kk = 0; kk < 2; ++kk) {
      s16x8 pa[2];
      #pragma unroll
      for (int r = 0; r < 2; ++r)
        pa[r] = *(const s16x8*)(&P[(16 * r + c15) * 72 + 32 * kk + 8 * g]);
      s16x8 vf[4];
      #pragma unroll
      for (int f = 0; f < 4; ++f)
        vf[f] = *(const s16x8*)(Vtb + (size_t)(16 * f + c15) * 4096 + kv0 + 32 * kk + 8 * g);
      #pragma unroll
      for (int r = 0; r < 2; ++r)
        #pragma unroll
        for (int f = 0; f < 4; ++f)
          o[r][f] = __builtin_amdgcn_mfma_f32_16x16x32_bf16(pa[r], vf[f], o[r][f], 0, 0, 0);
    }
  }

  // ---- all waves done with P before slabs overwrite the union ----
  __syncthreads();

  // stage 1: waves 4..7 publish partials into slab slot w-4
  if (w >= 4) {
    const int ws = w - 4;
    if (c15 == 0) {
      #pragma unroll
      for (int r = 0; r < 2; ++r)
        #pragma unroll
        for (int j = 0; j < 4; ++j) {
          const int row = 16 * r + 4 * g + j;
          msh[ws * 32 + row] = mrow[r][j];
          lsh[ws * 32 + row] = lrow[r][j];
        }
    }
    #pragma unroll
    for (int r = 0; r < 2; ++r)
      #pragma unroll
      for (int f = 0; f < 4; ++f)
        #pragma unroll
        for (int j = 0; j < 4; ++j) {
          const int row = 16 * r + 4 * g + j;
          osl[(ws * 32 + row) * 64 + 16 * f + c15] = o[r][f][j];
        }
  }
  __syncthreads();

  // stage 2: waves 0..3 merge partner (w+4) in-register, republish slot w
  if (w < 4) {
    #pragma unroll
    for (int r = 0; r < 2; ++r)
      #pragma unroll
      for (int j = 0; j < 4; ++j) {
        const int row = 16 * r + 4 * g + j;
        const float mp = msh[w * 32 + row];
        const float lp = lsh[w * 32 + row];
        const float mn = fmaxf(mrow[r][j], mp);
        const float aa = exp2f(mrow[r][j] - mn);
        const float ab = exp2f(mp - mn);
        #pragma unroll
        for (int f = 0; f < 4; ++f)
          o[r][f][j] = o[r][f][j] * aa + osl[(w * 32 + row) * 64 + 16 * f + c15] * ab;
        lrow[r][j] = lrow[r][j] * aa + lp * ab;
        mrow[r][j] = mn;
      }
    if (c15 == 0) {
      #pragma unroll
      for (int r = 0; r < 2; ++r)
        #pragma unroll
        for (int j = 0; j < 4; ++j) {
          const int row = 16 * r + 4 * g + j;
          msh[w * 32 + row] = mrow[r][j];
          lsh[w * 32 + row] = lrow[r][j];
        }
    }
    #pragma unroll
    for (int r = 0; r < 2; ++r)
      #pragma unroll
      for (int f = 0; f < 4; ++f)
        #pragma unroll
        for (int j = 0; j < 4; ++j) {
          const int row = 16 * r + 4 * g + j;
          osl[(w * 32 + row) * 64 + 16 * f + c15] = o[r][f][j];
        }
  }
  __syncthreads();

  // final 4-way merge: 512 threads; thread -> (row = t>>4, cols 4*(t&15)..+3)
  {
    const int row = t >> 4;
    const int cb = (t & 15) * 4;
    float m0v = msh[row], m1v = msh[32 + row], m2v = msh[64 + row], m3v = msh[96 + row];
    float M = fmaxf(fmaxf(m0v, m1v), fmaxf(m2v, m3v));
    float a0 = exp2f(m0v - M), a1 = exp2f(m1v - M), a2 = exp2f(m2v - M), a3 = exp2f(m3v - M);
    float L = a0 * lsh[row] + a1 * lsh[32 + row] + a2 * lsh[64 + row] + a3 * lsh[96 + row];
    const float inv = 1.0f / L;
    float* op = out + (size_t)(b * 4096 + q0 + row) * 64 + cb;
    #pragma unroll
    for (int c = 0; c < 4; ++c) {
      float v = a0 * osl[(row) * 64 + cb + c] + a1 * osl[(32 + row) * 64 + cb + c] +
                a2 * osl[(64 + row) * 64 + cb + c] + a3 * osl[(96 + row) * 64 + cb + c];
      op[c] = v * inv;
    }
  }
}

// ---------------- launch ------------------------------------------------------
extern "C" void kernel_launch(void* const* d_in, const int* in_sizes, int n_in,
                              void* d_out, int out_size, void* d_ws, size_t ws_size,
                              hipStream_t stream) {
  const float* x  = (const float*)d_in[0];
  const float* Wq = (const float*)d_in[1];
  const float* Wk = (const float*)d_in[2];
  const float* Wv = (const float*)d_in[3];
  float* out = (float*)d_out;

  char* ws = (char*)d_ws;
  u16* Wt = (u16*)(ws);                 // 294912 B
  u16* Qs = (u16*)(ws + 524288);        // 2 MB
  u16* Kb = (u16*)(ws + 2621440);       // 2 MB
  u16* Vt = (u16*)(ws + 4718592);       // 2 MB (transposed [b][64][4096])

  wconv_kernel<<<144, 256, 0, stream>>>(Wq, Wk, Wv, Wt);
  proj_kernel<<<256, 512, 0, stream>>>(x, Wt, Qs, Kb, Vt);
  attn_kernel<<<512, 512, 0, stream>>>(Qs, Kb, Vt, out);
}

// Round 15
// 160.844 us; speedup vs baseline: 2.6253x; 1.1484x over previous
//
#include <hip/hip_runtime.h>

typedef unsigned short u16;
typedef unsigned int u32;
typedef __attribute__((ext_vector_type(4))) float f32x4;
typedef __attribute__((ext_vector_type(8))) short s16x8;
typedef __attribute__((ext_vector_type(4))) u16 u16x4;
typedef __attribute__((ext_vector_type(4))) u32 u32x4;

#define SCALE_LOG2E (0.125f * 1.44269504088896340736f)
#define NEGBIG (-3.0e38f)

__device__ inline u16 f2bf(float f) {
  u32 u = __builtin_bit_cast(u32, f);
  u += 0x7fffu + ((u >> 16) & 1u);
  return (u16)(u >> 16);
}

// ---------------- kernel 0: W f32 -> bf16, transposed [n][k], Wq pre-scaled ----
__global__ void wconv_kernel(const float* __restrict__ Wq, const float* __restrict__ Wk,
                             const float* __restrict__ Wv, u16* __restrict__ Wt) {
  int base = blockIdx.x * 1024 + threadIdx.x;
  #pragma unroll
  for (int i = 0; i < 4; ++i) {
    int idx = base + i * 256;           // 144*1024 = 147456 = 192*768
    int n = idx / 768, k = idx - n * 768;
    int m = n >> 6, c = n & 63;
    const float* W = (m == 0) ? Wq : (m == 1 ? Wk : Wv);
    float v = W[k * 64 + c];
    if (m == 0) v *= SCALE_LOG2E;
    Wt[idx] = f2bf(v);
  }
}

// ---------------- kernel 1: QKV projection, software-prefetched ---------------
__global__ __launch_bounds__(512) void proj_kernel(const float* __restrict__ x,
                                                   const u16* __restrict__ Wt,
                                                   u16* __restrict__ Qs,
                                                   u16* __restrict__ Kb,
                                                   u16* __restrict__ Vt) {
  __shared__ __align__(16) u16 xT[64 * 64];
  __shared__ __align__(16) u16 Wl[192 * 64];

  const int t = threadIdx.x;
  const int lane = t & 63;
  const int wv = t >> 6;
  const int c15 = lane & 15, g = lane >> 4;
  const int mg = wv >> 1, nh = wv & 1;
  const int m0 = blockIdx.x * 64;

  f32x4 acc[6];
  #pragma unroll
  for (int f = 0; f < 6; ++f) acc[f] = 0.0f;

  const int xr = t >> 3;
  const int xc = (t & 7) * 8;

  // preload kt = 0
  f32x4 a0, a1;
  u32x4 wch[3];
  {
    const float* xp = x + (size_t)(m0 + xr) * 768 + xc;
    a0 = *(const f32x4*)(xp);
    a1 = *(const f32x4*)(xp + 4);
    #pragma unroll
    for (int i = 0; i < 3; ++i) {
      int ci = t + i * 512;
      int rw = ci >> 3, ch = ci & 7;
      wch[i] = *(const u32x4*)(Wt + rw * 768 + ch * 8);
    }
  }

  for (int kt = 0; kt < 12; ++kt) {
    __syncthreads();   // prev iter's LDS reads done
    // ---- write current tile to LDS ----
    {
      u32x4 px;
      px.x = (u32)f2bf(a0.x) | ((u32)f2bf(a0.y) << 16);
      px.y = (u32)f2bf(a0.z) | ((u32)f2bf(a0.w) << 16);
      px.z = (u32)f2bf(a1.x) | ((u32)f2bf(a1.y) << 16);
      px.w = (u32)f2bf(a1.z) | ((u32)f2bf(a1.w) << 16);
      int ch = t & 7;
      int sw = ch ^ (xr & 7);
      *(u32x4*)(&xT[xr * 64 + sw * 8]) = px;
    }
    #pragma unroll
    for (int i = 0; i < 3; ++i) {
      int ci = t + i * 512;
      int rw = ci >> 3, ch = ci & 7;
      int sw = ch ^ (rw & 7);
      *(u32x4*)(&Wl[rw * 64 + sw * 8]) = wch[i];
    }
    // ---- prefetch next tile (overlaps barrier + MFMA) ----
    if (kt < 11) {
      const int k0 = (kt + 1) * 64;
      const float* xp = x + (size_t)(m0 + xr) * 768 + k0 + xc;
      a0 = *(const f32x4*)(xp);
      a1 = *(const f32x4*)(xp + 4);
      #pragma unroll
      for (int i = 0; i < 3; ++i) {
        int ci = t + i * 512;
        int rw = ci >> 3, ch = ci & 7;
        wch[i] = *(const u32x4*)(Wt + rw * 768 + k0 + ch * 8);
      }
    }
    __syncthreads();
    // ---- MFMA ----
    #pragma unroll
    for (int kk = 0; kk < 2; ++kk) {
      const int arow = 16 * mg + c15;
      s16x8 af = *(const s16x8*)(&xT[arow * 64 + (((kk * 4 + g) ^ (arow & 7)) * 8)]);
      #pragma unroll
      for (int f = 0; f < 6; ++f) {
        const int brow = 96 * nh + 16 * f + c15;
        s16x8 bf = *(const s16x8*)(&Wl[brow * 64 + (((kk * 4 + g) ^ (brow & 7)) * 8)]);
        acc[f] = __builtin_amdgcn_mfma_f32_16x16x32_bf16(af, bf, acc[f], 0, 0, 0);
      }
    }
  }

  const int b = m0 >> 12;
  const int s0 = m0 & 4095;
  const int mbase = m0 + 16 * mg + 4 * g;
  #pragma unroll
  for (int f = 0; f < 6; ++f) {
    const int n16 = 96 * nh + 16 * f;
    if (n16 < 64) {
      const int coln = n16 + c15;
      #pragma unroll
      for (int j = 0; j < 4; ++j)
        Qs[(size_t)(mbase + j) * 64 + coln] = f2bf(acc[f][j]);
    } else if (n16 < 128) {
      const int coln = n16 - 64 + c15;
      #pragma unroll
      for (int j = 0; j < 4; ++j)
        Kb[(size_t)(mbase + j) * 64 + coln] = f2bf(acc[f][j]);
    } else {
      const int d = n16 - 128 + c15;
      u16x4 pk;
      pk.x = f2bf(acc[f][0]); pk.y = f2bf(acc[f][1]);
      pk.z = f2bf(acc[f][2]); pk.w = f2bf(acc[f][3]);
      *(u16x4*)(Vt + (size_t)(b * 64 + d) * 4096 + s0 + 16 * mg + 4 * g) = pk;
    }
  }
}

// ---------------- kernel 2: causal flash attention, 8-wave KV split -----------
// 512 blocks of 8 waves (512 thr). Wave w processes KV tiles w, w+8, ...;
// longest chain = ceil(64/8) = 8 tiles. Two-stage in-LDS merge.
// launch_bounds min-waves = 2 (NOT 4): the ,4 cap forced 64 VGPRs -> 48 MB/dispatch
// scratch spills (R13 counters). At ~112 VGPR we still fit 4 waves/SIMD.
__global__ __launch_bounds__(512, 2) void attn_kernel(const u16* __restrict__ Qs,
                                                      const u16* __restrict__ Kb,
                                                      const u16* __restrict__ Vt,
                                                      float* __restrict__ out) {
  // union: during KV loop, per-wave P buffers [8][32*72] u16 (36864 B);
  // after the post-loop barrier, 4 slabs [4][32][64] f32 (32768) + stats (1024).
  __shared__ __align__(16) char smem[8 * 32 * 72 * 2];
  float* osl = (float*)smem;                       // [4][32][64]
  float* msh = (float*)(smem + 32768);             // [4][32]
  float* lsh = (float*)(smem + 32768 + 512);       // [4][32]

  const int t = threadIdx.x;
  const int lane = t & 63;
  const int w = t >> 6;                            // wave 0..7
  const int c15 = lane & 15, g = lane >> 4;
  const int bid = blockIdx.x;
  const int qb = 127 - (bid >> 2);                 // big blocks dispatched first
  const int b = bid & 3;
  const int q0 = qb * 32;

  u16* P = (u16*)smem + w * (32 * 72);             // per-wave P, padded stride 72

  const u16* Qb  = Qs + (size_t)b * 4096 * 64;
  const u16* Kbb = Kb + (size_t)b * 4096 * 64;
  const u16* Vtb = Vt + (size_t)b * 64 * 4096;

  // Q fragments in registers: A[q = c15 (+16r)][d = 32kk+8g+e]
  s16x8 qf[2][2];
  #pragma unroll
  for (int r = 0; r < 2; ++r)
    #pragma unroll
    for (int kk = 0; kk < 2; ++kk)
      qf[r][kk] = *(const s16x8*)(Qb + (size_t)(q0 + 16 * r + c15) * 64 + 32 * kk + 8 * g);

  f32x4 o[2][4];
  float mrow[2][4], lrow[2][4];
  #pragma unroll
  for (int r = 0; r < 2; ++r)
    #pragma unroll
    for (int j = 0; j < 4; ++j) {
      o[r][j] = 0.0f; mrow[r][j] = NEGBIG; lrow[r][j] = 0.0f;
    }

  const int T = (qb >> 1) + 1;                     // kv tiles of 64
  for (int tile = w; tile < T; tile += 8) {
    const int kv0 = tile * 64;
    // ---- S = Q K^T (pre-scaled by SCALE*log2e) ----
    f32x4 s[2][4];
    #pragma unroll
    for (int r = 0; r < 2; ++r)
      #pragma unroll
      for (int f = 0; f < 4; ++f) s[r][f] = 0.0f;
    #pragma unroll
    for (int kk = 0; kk < 2; ++kk) {
      s16x8 kf[4];
      #pragma unroll
      for (int f = 0; f < 4; ++f)
        kf[f] = *(const s16x8*)(Kbb + (size_t)(kv0 + 16 * f + c15) * 64 + 32 * kk + 8 * g);
      #pragma unroll
      for (int r = 0; r < 2; ++r)
        #pragma unroll
        for (int f = 0; f < 4; ++f)
          s[r][f] = __builtin_amdgcn_mfma_f32_16x16x32_bf16(qf[r][kk], kf[f], s[r][f], 0, 0, 0);
    }
    // ---- causal mask (diagonal tiles only) ----
    if (kv0 + 63 > q0) {
      #pragma unroll
      for (int r = 0; r < 2; ++r)
        #pragma unroll
        for (int f = 0; f < 4; ++f) {
          const int kcol = kv0 + 16 * f + c15;
          #pragma unroll
          for (int j = 0; j < 4; ++j) {
            const int qrow = q0 + 16 * r + 4 * g + j;
            if (kcol > qrow) s[r][f][j] = NEGBIG;
          }
        }
    }
    // ---- online softmax ----
    #pragma unroll
    for (int r = 0; r < 2; ++r)
      #pragma unroll
      for (int j = 0; j < 4; ++j) {
        float mx = fmaxf(fmaxf(s[r][0][j], s[r][1][j]), fmaxf(s[r][2][j], s[r][3][j]));
        mx = fmaxf(mx, __shfl_xor(mx, 1));
        mx = fmaxf(mx, __shfl_xor(mx, 2));
        mx = fmaxf(mx, __shfl_xor(mx, 4));
        mx = fmaxf(mx, __shfl_xor(mx, 8));
        const float mn = fmaxf(mrow[r][j], mx);
        const float al = exp2f(mrow[r][j] - mn);
        float ps[4], sum = 0.0f;
        #pragma unroll
        for (int f = 0; f < 4; ++f) { ps[f] = exp2f(s[r][f][j] - mn); sum += ps[f]; }
        sum += __shfl_xor(sum, 1);
        sum += __shfl_xor(sum, 2);
        sum += __shfl_xor(sum, 4);
        sum += __shfl_xor(sum, 8);
        lrow[r][j] = lrow[r][j] * al + sum;
        mrow[r][j] = mn;
        #pragma unroll
        for (int fd = 0; fd < 4; ++fd) o[r][fd][j] *= al;
        const int prow = 16 * r + 4 * g + j;
        #pragma unroll
        for (int f = 0; f < 4; ++f) {
          const float pn = __shfl_xor(ps[f], 1);
          if (!(lane & 1)) {
            const u32 pk = (u32)f2bf(ps[f]) | ((u32)f2bf(pn) << 16);
            *(u32*)(&P[prow * 72 + 16 * f + c15]) = pk;
          }
        }
      }
    // ---- O += P V ----
    #pragma unroll
    for (int kk = 0; kk < 2; ++kk) {
      s16x8 pa[2];
      #pragma unroll
      for (int r = 0; r < 2; ++r)
        pa[r] = *(const s16x8*)(&P[(16 * r + c15) * 72 + 32 * kk + 8 * g]);
      s16x8 vf[4];
      #pragma unroll
      for (int f = 0; f < 4; ++f)
        vf[f] = *(const s16x8*)(Vtb + (size_t)(16 * f + c15) * 4096 + kv0 + 32 * kk + 8 * g);
      #pragma unroll
      for (int r = 0; r < 2; ++r)
        #pragma unroll
        for (int f = 0; f < 4; ++f)
          o[r][f] = __builtin_amdgcn_mfma_f32_16x16x32_bf16(pa[r], vf[f], o[r][f], 0, 0, 0);
    }
  }

  // ---- all waves done with P before slabs overwrite the union ----
  __syncthreads();

  // stage 1: waves 4..7 publish partials into slab slot w-4
  if (w >= 4) {
    const int ws = w - 4;
    if (c15 == 0) {
      #pragma unroll
      for (int r = 0; r < 2; ++r)
        #pragma unroll
        for (int j = 0; j < 4; ++j) {
          const int row = 16 * r + 4 * g + j;
          msh[ws * 32 + row] = mrow[r][j];
          lsh[ws * 32 + row] = lrow[r][j];
        }
    }
    #pragma unroll
    for (int r = 0; r < 2; ++r)
      #pragma unroll
      for (int f = 0; f < 4; ++f)
        #pragma unroll
        for (int j = 0; j < 4; ++j) {
          const int row = 16 * r + 4 * g + j;
          osl[(ws * 32 + row) * 64 + 16 * f + c15] = o[r][f][j];
        }
  }
  __syncthreads();

  // stage 2: waves 0..3 merge partner (w+4) in-register, republish slot w
  if (w < 4) {
    #pragma unroll
    for (int r = 0; r < 2; ++r)
      #pragma unroll
      for (int j = 0; j < 4; ++j) {
        const int row = 16 * r + 4 * g + j;
        const float mp = msh[w * 32 + row];
        const float lp = lsh[w * 32 + row];
        const float mn = fmaxf(mrow[r][j], mp);
        const float aa = exp2f(mrow[r][j] - mn);
        const float ab = exp2f(mp - mn);
        #pragma unroll
        for (int f = 0; f < 4; ++f)
          o[r][f][j] = o[r][f][j] * aa + osl[(w * 32 + row) * 64 + 16 * f + c15] * ab;
        lrow[r][j] = lrow[r][j] * aa + lp * ab;
        mrow[r][j] = mn;
      }
    if (c15 == 0) {
      #pragma unroll
      for (int r = 0; r < 2; ++r)
        #pragma unroll
        for (int j = 0; j < 4; ++j) {
          const int row = 16 * r + 4 * g + j;
          msh[w * 32 + row] = mrow[r][j];
          lsh[w * 32 + row] = lrow[r][j];
        }
    }
    #pragma unroll
    for (int r = 0; r < 2; ++r)
      #pragma unroll
      for (int f = 0; f < 4; ++f)
        #pragma unroll
        for (int j = 0; j < 4; ++j) {
          const int row = 16 * r + 4 * g + j;
          osl[(w * 32 + row) * 64 + 16 * f + c15] = o[r][f][j];
        }
  }
  __syncthreads();

  // final 4-way merge: 512 threads; thread -> (row = t>>4, cols 4*(t&15)..+3)
  {
    const int row = t >> 4;
    const int cb = (t & 15) * 4;
    float m0v = msh[row], m1v = msh[32 + row], m2v = msh[64 + row], m3v = msh[96 + row];
    float M = fmaxf(fmaxf(m0v, m1v), fmaxf(m2v, m3v));
    float a0 = exp2f(m0v - M), a1 = exp2f(m1v - M), a2 = exp2f(m2v - M), a3 = exp2f(m3v - M);
    float L = a0 * lsh[row] + a1 * lsh[32 + row] + a2 * lsh[64 + row] + a3 * lsh[96 + row];
    const float inv = 1.0f / L;
    float* op = out + (size_t)(b * 4096 + q0 + row) * 64 + cb;
    #pragma unroll
    for (int c = 0; c < 4; ++c) {
      float v = a0 * osl[(row) * 64 + cb + c] + a1 * osl[(32 + row) * 64 + cb + c] +
                a2 * osl[(64 + row) * 64 + cb + c] + a3 * osl[(96 + row) * 64 + cb + c];
      op[c] = v * inv;
    }
  }
}

// ---------------- launch ------------------------------------------------------
extern "C" void kernel_launch(void* const* d_in, const int* in_sizes, int n_in,
                              void* d_out, int out_size, void* d_ws, size_t ws_size,
                              hipStream_t stream) {
  const float* x  = (const float*)d_in[0];
  const float* Wq = (const float*)d_in[1];
  const float* Wk = (const float*)d_in[2];
  const float* Wv = (const float*)d_in[3];
  float* out = (float*)d_out;

  char* ws = (char*)d_ws;
  u16* Wt = (u16*)(ws);                 // 294912 B
  u16* Qs = (u16*)(ws + 524288);        // 2 MB
  u16* Kb = (u16*)(ws + 2621440);       // 2 MB
  u16* Vt = (u16*)(ws + 4718592);       // 2 MB (transposed [b][64][4096])

  wconv_kernel<<<144, 256, 0, stream>>>(Wq, Wk, Wv, Wt);
  proj_kernel<<<256, 512, 0, stream>>>(x, Wt, Qs, Kb, Vt);
  attn_kernel<<<512, 512, 0, stream>>>(Qs, Kb, Vt, out);
}